// Round 9
// baseline (669.236 us; speedup 1.0000x reference)
//
#include <hip/hip_runtime.h>

// T=512, B=512, K=8, V=5, H=30, NL=4, NLAB=3
#define TT 512
#define BB 512
#define KK 8
#define HH 30
#define GG 120
#define NLAYER 4
#define NS 16       // samples per pipeline block
#define SBN 32      // pipeline blocks (SBN*NS = BB)
#define RING 32     // h-ring depth (steps)
#define PRIME 12    // extra skew the consumer demands beyond need
#define BACK 24     // producer may run this far past consumer flag

typedef _Float16 f16x8 __attribute__((ext_vector_type(8)));
typedef _Float16 f16x2 __attribute__((ext_vector_type(2)));
typedef float    f32x4 __attribute__((ext_vector_type(4)));

// d_ws (halfs): [0, SEQSZ) seq, overwritten in place by layer-3 h (layer-3
// writes trail layer-0 reads by ~36+ steps); A-fragments after.
#define SEQSZ_H    (SBN*TT*NS*32)       // 16 MB
#define FRAG_OFF_H SEQSZ_H              // 4*8*64*2*8 halfs = 64 KB

__device__ __forceinline__ float rcp_f(float x){ return __builtin_amdgcn_rcpf(x); }
__device__ __forceinline__ int pack2h(float a, float b){
    return __builtin_bit_cast(int, __builtin_amdgcn_cvt_pkrtz(a, b));
}

// ---------------- kernel 1: embed-pool -> seq + A-fragment prep -------------
// Tile u (0..7): gate = u>>1 (i,i,f,f,g,g,o,o), A-row m -> unit 2m+(u&1).
// cols: k<30 Wih (a0h) / Whh (a1h); k==30 bias in a1h (b-frag k=30 slot = 1);
// k==31 zero. D-layout == B-frag layout: lane(n,q) produces h for units
// 8q+2r+(u&1) of sample n == its own next B-fragment. (R7-verified mapping.)
__global__ __launch_bounds__(256) void prep_kernel(
    const int* __restrict__ xin, const float* __restrict__ wxin,
    const float* __restrict__ embed,
    const float* __restrict__ Wih, const float* __restrict__ Whh,
    const float* __restrict__ bih, const float* __restrict__ bhh,
    _Float16* __restrict__ wsh)
{
    const int tid = threadIdx.x;
    if (blockIdx.x == SBN*32) {            // ---- frag-prep block ----
        const int L = tid >> 6, lane = tid & 63;
        const int mA = lane & 15, qq = lane >> 4;
        const float* WihL = Wih + L*GG*HH;
        const float* WhhL = Whh + L*GG*HH;
        _Float16* fr = wsh + FRAG_OFF_H;
        #pragma unroll
        for (int u = 0; u < 8; ++u) {
            const int gate = u >> 1;
            const int unit = 2*mA + (u & 1);
            const bool valid = (unit < HH);
            const int src = gate*HH + unit;
            f16x8 a0hv, a1hv;
            #pragma unroll
            for (int jj = 0; jj < 8; ++jj) {
                const int k = qq*8 + jj;
                float v0 = (valid && k < HH) ? WihL[src*HH + k] : 0.f;
                a0hv[jj] = (_Float16)v0;
                float v1 = 0.f;
                if (valid) {
                    if (k < HH)       v1 = WhhL[src*HH + k];
                    else if (k == HH) v1 = bih[L*GG + src] + bhh[L*GG + src];
                }
                a1hv[jj] = (_Float16)v1;
            }
            const int idx = ((L*8 + u)*64 + lane)*2;
            *(f16x8*)(fr + (size_t)(idx+0)*8) = a0hv;
            *(f16x8*)(fr + (size_t)(idx+1)*8) = a1hv;
        }
        return;
    }
    // ---- embed-pool blocks: 32 sb x 32 tchunks ----
    __shared__ float re_s[5*HH];
    if (tid < 5*HH) re_s[tid] = fmaxf(embed[tid], 0.f);
    __syncthreads();
    const int sb = blockIdx.x >> 5, tc = blockIdx.x & 31;
    const int tt = tid >> 4, n = tid & 15;
    const int t = tc*16 + tt;
    const int b = sb*NS + n;
    const int4*   xp = (const int4*)  (xin  + ((size_t)t*BB + b)*KK);
    const float4* wp = (const float4*)(wxin + ((size_t)t*BB + b)*KK);
    const int4  xa = xp[0], xb = xp[1];
    const float4 wa = wp[0], wb = wp[1];
    float acc[HH];
    #pragma unroll
    for (int j = 0; j < HH; ++j) acc[j] = 0.f;
    const int   xv[8]  = {xa.x, xa.y, xa.z, xa.w, xb.x, xb.y, xb.z, xb.w};
    const float wv8[8] = {wa.x, wa.y, wa.z, wa.w, wb.x, wb.y, wb.z, wb.w};
    #pragma unroll
    for (int k = 0; k < 8; ++k) {
        const float* row = re_s + xv[k]*HH;
        const float w = wv8[k];
        #pragma unroll
        for (int j = 0; j < HH; ++j) acc[j] = fmaf(row[j], w, acc[j]);
    }
    int s[16];
    #pragma unroll
    for (int jp = 0; jp < 15; ++jp)
        s[jp] = pack2h(acc[2*jp]*0.125f, acc[2*jp+1]*0.125f);
    s[15] = 0;                                       // k=30,31 zero
    int4* dst = (int4*)(wsh + (((size_t)sb*TT + t)*NS + n)*32);
    dst[0] = make_int4(s[0],  s[1],  s[2],  s[3]);
    dst[1] = make_int4(s[4],  s[5],  s[6],  s[7]);
    dst[2] = make_int4(s[8],  s[9],  s[10], s[11]);
    dst[3] = make_int4(s[12], s[13], s[14], s[15]);
}

// ---------------- kernel 2: 4-wave layer pipeline + fused attention ---------
__global__ __launch_bounds__(256, 1) void rnn_pipe(
    _Float16* __restrict__ wsh,
    const float* __restrict__ W1, const float* __restrict__ b1,
    const float* __restrict__ W2,
    const float* __restrict__ fcW, const float* __restrict__ fcb,
    float* __restrict__ out)
{
    __shared__ alignas(16) _Float16 ring_s[3][RING][NS][32];  // 96 KB
    __shared__ float energy_s[NS][TT];                        // 32 KB
    __shared__ int vp_s[NLAYER], vc_s[NLAYER];

    const int tid  = threadIdx.x;
    const int L    = tid >> 6, lane = tid & 63;
    const int n    = lane & 15, q = lane >> 4;
    const int sb   = blockIdx.x;

    if (tid < NLAYER) { vp_s[tid] = 0; vc_s[tid] = 0; }

    f16x8 a0h[8], a1h[8];
    {
        const _Float16* fr = wsh + FRAG_OFF_H;
        #pragma unroll
        for (int u = 0; u < 8; ++u) {
            const int idx = ((L*8 + u)*64 + lane)*2;
            a0h[u] = *(const f16x8*)(fr + (size_t)(idx+0)*8);
            a1h[u] = *(const f16x8*)(fr + (size_t)(idx+1)*8);
        }
    }
    const _Float16* seqb = wsh + (size_t)sb*TT*NS*32 + n*32 + q*8;
    _Float16*       h3w  = wsh + (size_t)sb*TT*NS*32;
    __syncthreads();

    // shared-rcp LSTM: c' = sig(F)c + sig(I)tanh(G); h = sig(O)tanh(c')
    auto lstm_unit = [&](float I, float F, float G, float O, float& c) -> float {
        const float P  = __expf(-I);
        const float E  = __expf(fminf(2.f*G, 60.f));
        const float Fs = rcp_f(1.f + __expf(-F));
        const float pig = (E - 1.f) * rcp_f((1.f + P)*(1.f + E));
        c = fmaf(Fs, c, pig);
        const float C2 = __expf(fminf(2.f*c, 60.f));
        const float Qo = __expf(-O);
        return (C2 - 1.f) * rcp_f((1.f + Qo)*(1.f + C2));
    };

    const int BIAS1 = 0x00003C00;            // halfs (1.0, 0.0) at k=30,31
    int4 bhw = make_int4(0, 0, 0, (q == 3) ? BIAS1 : 0);   // self h hi B-frag
    int4 blw = make_int4(0, 0, 0, 0);                      // self h lo B-frag
    float cE[4] = {0,0,0,0}, cO[4] = {0,0,0,0};

    int4 cur[4], nxt[4];
    if (L == 0) {
        #pragma unroll
        for (int i = 0; i < 4; ++i) {
            cur[i] = *(const int4*)(seqb + (size_t)(i)*(NS*32));
            nxt[i] = *(const int4*)(seqb + (size_t)(4+i)*(NS*32));
        }
    }
    volatile int* vp = vp_s;
    volatile int* vc = vc_s;

    for (int T0 = 0; T0 < TT; T0 += 4) {
        if (L > 0) {                  // primed-skew wait: needs T0+4, demands more
            const int req = (T0 + 4 + PRIME < TT) ? (T0 + 4 + PRIME) : TT;
            while (vp[L-1] < req) __builtin_amdgcn_s_sleep(2);
        }
        if (L < 3) {                  // backpressure (ring safety: BACK+3 < RING)
            while (vc[L+1] < T0 - BACK) __builtin_amdgcn_s_sleep(2);
        }
        asm volatile("" ::: "memory");

        f16x8 b0[4];
        if (L == 0) {
            #pragma unroll
            for (int i = 0; i < 4; ++i) b0[i] = __builtin_bit_cast(f16x8, cur[i]);
            #pragma unroll
            for (int i = 0; i < 4; ++i) cur[i] = nxt[i];
            #pragma unroll
            for (int i = 0; i < 4; ++i) {
                int ti = T0 + 8 + i; ti = (ti < TT) ? ti : (TT - 1);
                nxt[i] = *(const int4*)(seqb + (size_t)ti*(NS*32));
            }
        } else {
            #pragma unroll
            for (int i = 0; i < 4; ++i)
                b0[i] = *(const f16x8*)&ring_s[L-1][(T0+i) & (RING-1)][n][q*8];
        }

        f32x4 U[8];
        #pragma unroll
        for (int u = 0; u < 8; ++u) {
            f32x4 z = {0.f,0.f,0.f,0.f};
            U[u] = __builtin_amdgcn_mfma_f32_16x16x32_f16(a0h[u], b0[0], z, 0,0,0);
        }
        #pragma unroll
        for (int tt = 0; tt < 4; ++tt) {
            const int t = T0 + tt;
            const f16x8 bhf = __builtin_bit_cast(f16x8, bhw);
            const f16x8 blf = __builtin_bit_cast(f16x8, blw);
            f32x4 acc[8];
            #pragma unroll
            for (int u = 0; u < 8; ++u) {
                f32x4 d = __builtin_amdgcn_mfma_f32_16x16x32_f16(a1h[u], bhf, U[u], 0,0,0);
                acc[u]  = __builtin_amdgcn_mfma_f32_16x16x32_f16(a1h[u], blf, d,    0,0,0);
            }
            if (tt < 3) {             // U for next step overlaps this step's acts
                #pragma unroll
                for (int u = 0; u < 8; ++u) {
                    f32x4 z = {0.f,0.f,0.f,0.f};
                    U[u] = __builtin_amdgcn_mfma_f32_16x16x32_f16(a0h[u], b0[tt+1], z, 0,0,0);
                }
            }
            int hi[4], lo[4];
            #pragma unroll
            for (int r = 0; r < 4; ++r) {   // units 8q+2r, 8q+2r+1 of sample n
                const float hE = lstm_unit(acc[0][r], acc[2][r], acc[4][r], acc[6][r], cE[r]);
                const float hO = lstm_unit(acc[1][r], acc[3][r], acc[5][r], acc[7][r], cO[r]);
                const int hp = pack2h(hE, hO);
                const f16x2 hh = __builtin_bit_cast(f16x2, hp);
                hi[r] = hp;
                lo[r] = pack2h(hE - (float)hh[0], hO - (float)hh[1]);
            }
            bhw = make_int4(hi[0], hi[1], hi[2], (q == 3) ? BIAS1 : hi[3]);
            blw = make_int4(lo[0], lo[1], lo[2], (q == 3) ? 0     : lo[3]);
            const int4 hout = make_int4(hi[0], hi[1], hi[2], hi[3]);
            if (L < 3) *(int4*)&ring_s[L][t & (RING-1)][n][q*8] = hout;
            else *(int4*)(h3w + (size_t)t*(NS*32) + n*32 + q*8) = hout;
        }
        if (L < 3) {
            asm volatile("s_waitcnt lgkmcnt(0)" ::: "memory");
            if (lane == 0) vp[L] = T0 + 4;
        }
        if (L > 0) {
            if (lane == 0) vc[L] = T0 + 4;
        }
    }

    // ================= fused attention (4 waves x 4 samples) =================
    asm volatile("s_waitcnt vmcnt(0) lgkmcnt(0)" ::: "memory");
    __syncthreads();

    f16x8 w1f[4];
    #pragma unroll
    for (int v = 0; v < 4; ++v)
        #pragma unroll
        for (int jj = 0; jj < 8; ++jj) {
            const int k = q*8 + jj;
            w1f[v][jj] = (k < HH) ? (_Float16)W1[k*64 + 16*v + n] : (_Float16)0;
        }
    float b1r[4][4], w2r[4][4];
    #pragma unroll
    for (int v = 0; v < 4; ++v)
        #pragma unroll
        for (int r = 0; r < 4; ++r) {
            const int u = 16*v + 4*q + r;
            b1r[v][r] = b1[u];
            w2r[v][r] = W2[u];
        }
    const _Float16* h3b = h3w;
    #pragma unroll
    for (int ns = 0; ns < 4; ++ns) {
        const int smp = L*4 + ns;
        for (int t0 = 0; t0 < TT; t0 += 16) {
            const f16x8 hf = *(const f16x8*)(h3b + (size_t)(t0 + n)*(NS*32) + smp*32 + q*8);
            float part = 0.f;
            #pragma unroll
            for (int v = 0; v < 4; ++v) {
                f32x4 z = {0.f,0.f,0.f,0.f};
                f32x4 d = __builtin_amdgcn_mfma_f32_16x16x32_f16(w1f[v], hf, z, 0,0,0);
                #pragma unroll
                for (int r = 0; r < 4; ++r)
                    part += fmaxf(d[r] + b1r[v][r], 0.f) * w2r[v][r];
            }
            part += __shfl_xor(part, 16, 64);
            part += __shfl_xor(part, 32, 64);
            if (q == 0) energy_s[smp][t0 + n] = part;   // b2 cancels in softmax
        }
    }
    __syncthreads();

    #pragma unroll
    for (int ns = 0; ns < 4; ++ns) {
        const int smp = L*4 + ns;
        float ev[8];
        float mx = -3.0e38f;
        #pragma unroll
        for (int k2 = 0; k2 < 8; ++k2) {
            ev[k2] = energy_s[smp][k2*64 + lane];
            mx = fmaxf(mx, ev[k2]);
        }
        #pragma unroll
        for (int m = 1; m < 64; m <<= 1) mx = fmaxf(mx, __shfl_xor(mx, m, 64));
        float ss = 0.f;
        #pragma unroll
        for (int k2 = 0; k2 < 8; ++k2) { ev[k2] = __expf(ev[k2] - mx); ss += ev[k2]; }
        #pragma unroll
        for (int m = 1; m < 64; m <<= 1) ss += __shfl_xor(ss, m, 64);
        const float invS = rcp_f(ss);
        float plx[15], ply[15];
        #pragma unroll
        for (int k = 0; k < 15; ++k) { plx[k] = 0.f; ply[k] = 0.f; }
        #pragma unroll
        for (int k2 = 0; k2 < 8; ++k2) {
            const int t = k2*64 + lane;
            const float w = ev[k2] * invS;
            const int* hp = (const int*)(h3b + (size_t)t*(NS*32) + smp*32);
            #pragma unroll
            for (int k = 0; k < 15; ++k) {
                const f16x2 hh = __builtin_bit_cast(f16x2, hp[k]);
                plx[k] = fmaf(w, (float)hh[0], plx[k]);
                ply[k] = fmaf(w, (float)hh[1], ply[k]);
            }
        }
        #pragma unroll
        for (int m = 1; m < 64; m <<= 1) {
            #pragma unroll
            for (int k = 0; k < 15; ++k) {
                plx[k] += __shfl_xor(plx[k], m, 64);
                ply[k] += __shfl_xor(ply[k], m, 64);
            }
        }
        if (lane == 0) {
            float lg[3];
            #pragma unroll
            for (int i = 0; i < 3; ++i) {
                float a = fcb[i];
                #pragma unroll
                for (int k = 0; k < 15; ++k) {
                    a = fmaf(plx[k], fcW[(2*k)*3 + i], a);
                    a = fmaf(ply[k], fcW[(2*k+1)*3 + i], a);
                }
                lg[i] = a;
            }
            const float m3 = fmaxf(lg[0], fmaxf(lg[1], lg[2]));
            const float e0 = __expf(lg[0]-m3), e1 = __expf(lg[1]-m3), e2 = __expf(lg[2]-m3);
            const float inv = rcp_f(e0 + e1 + e2);
            const int bg = (sb*NS + smp)*3;
            out[bg+0] = e0*inv; out[bg+1] = e1*inv; out[bg+2] = e2*inv;
        }
    }
}

extern "C" void kernel_launch(void* const* d_in, const int* in_sizes, int n_in,
                              void* d_out, int out_size, void* d_ws, size_t ws_size,
                              hipStream_t stream)
{
    (void)in_sizes; (void)n_in; (void)ws_size; (void)out_size;
    _Float16* wsh = (_Float16*)d_ws;
    prep_kernel<<<SBN*32 + 1, 256, 0, stream>>>(
        (const int*)  d_in[0], (const float*)d_in[1], (const float*)d_in[2],
        (const float*)d_in[3], (const float*)d_in[4], (const float*)d_in[5],
        (const float*)d_in[6], wsh);
    rnn_pipe<<<SBN, 256, 0, stream>>>(
        wsh, (const float*)d_in[7], (const float*)d_in[8], (const float*)d_in[9],
        (const float*)d_in[11], (const float*)d_in[12], (float*)d_out);
}